// Round 2
// 515.352 us; speedup vs baseline: 1.0264x; 1.0264x over previous
//
#include <hip/hip_runtime.h>
#include <hip/hip_bf16.h>
#include <math.h>

// LineRWKVBlock: y = (x + sigmoid(x@Wr) * scan(x@Wv)) ; y += y@Wc
// B=16, W=2048, D=1024, decay=0.99.
//
// R4 = R3 resubmission (R3 failed at container level with no kernel-side
// evidence; schedule re-audited: uniform barriers, exact vmcnt ledger,
// in-bounds LDS/global).  GEMM structure: 256^2-tile BK=32 8-wave
// phase-pipelined schedule (T2+T3+T4+T5):
//   - 4 phases per K-tile: {ds_read subtile | stage 1 half-tile | bar | 8 MFMA | bar}
//   - counted s_waitcnt vmcnt(3) once per K-tile (never 0 in main loop); staging
//     runs 2 K-tiles ahead, writing into half-regions consumed >=1 barrier earlier
//   - LDS XOR swizzle byte^=((row>>1)&3)<<4 (both-sides: pre-swizzled global src
//     for linear global_load_lds + swizzled ds_read addr) -> 2-way residual
//   - s_setprio(1) around each MFMA cluster
// Other kernels (prep/scan) unchanged, near BW-bound.
//
// ws: WT 6 MiB | Xb 64 | V/y_tmp 64 | R 64 | sl 1 | s_in 1  = 200 MiB

#define MROWS 32768           // B*W
#define NCHUNK 16
#define CHUNKL 128
#define DECAY_F 0.99f
#define OM_F 0.01f

typedef __attribute__((ext_vector_type(8))) short short8;   // 8 bf16 (4 VGPRs)
typedef __attribute__((ext_vector_type(4))) float floatx4;

using bf16 = __hip_bfloat16;
using bf162 = __hip_bfloat162;

// async global->LDS, 16B per lane; lds base wave-uniform, HW scatters lane i at
// base + i*16.
__device__ __forceinline__ void async_copy16(const void* g, void* l) {
  __builtin_amdgcn_global_load_lds(
      (const __attribute__((address_space(1))) unsigned int*)g,
      (__attribute__((address_space(3))) unsigned int*)l, 16, 0, 0);
}

#define S_BARRIER() asm volatile("s_barrier" ::: "memory")
#define VMCNT3()                                                               \
  do {                                                                         \
    asm volatile("s_waitcnt vmcnt(3)" ::: "memory");                           \
    __builtin_amdgcn_sched_barrier(0);                                         \
  } while (0)
#define VMCNT0()                                                               \
  do {                                                                         \
    asm volatile("s_waitcnt vmcnt(0)" ::: "memory");                           \
    __builtin_amdgcn_sched_barrier(0);                                         \
  } while (0)

// ---------------- kernel 1: x fp32 -> bf16 ----------------
__global__ void prep_x(const float* __restrict__ X, bf16* __restrict__ Xb) {
  const int idx = blockIdx.x * 256 + threadIdx.x;   // 8388608 float4-groups
  const float4 v = ((const float4*)X)[idx];
  union { ushort4 u; bf16 h[4]; } pk;
  pk.h[0] = __float2bfloat16(v.x);
  pk.h[1] = __float2bfloat16(v.y);
  pk.h[2] = __float2bfloat16(v.z);
  pk.h[3] = __float2bfloat16(v.w);
  ((ushort4*)Xb)[idx] = pk.u;
}

// ---------------- kernel 2: weight transpose + bf16 cast ----------------
// WT rows 0..1023 = Wv^T, 1024..2047 = Wr^T, 2048..3071 = Wc^T ; WT[n][k]
__global__ void prep_weights(const float* __restrict__ Wv,
                             const float* __restrict__ Wr,
                             const float* __restrict__ Wc,
                             bf16* __restrict__ WT) {
  __shared__ float tile[32][33];
  const int bk = blockIdx.x * 32;   // k block
  const int bn = blockIdx.y * 32;   // global n block (0..3071)
  const float* src;
  int nbase = bn;
  if (bn < 1024)      { src = Wv; }
  else if (bn < 2048) { src = Wr; nbase = bn - 1024; }
  else                { src = Wc; nbase = bn - 2048; }
  const int tx = threadIdx.x;       // 32
  const int ty = threadIdx.y;       // 8
  #pragma unroll
  for (int i = ty; i < 32; i += 8)
    tile[i][tx] = src[(size_t)(bk + i) * 1024 + nbase + tx];  // tile[k][n]
  __syncthreads();
  #pragma unroll
  for (int i = ty; i < 32; i += 8)
    WT[(size_t)(bn + i) * 1024 + bk + tx] = __float2bfloat16(tile[tx][i]);
}

// ---------------- kernels 3/7: 256^2 BK=32 phase-pipelined GEMM ------------
// MODE 0: v/r GEMM  -> Vout bf16 (nt<4), Rout = sigmoid (nt>=4); N=2048
// MODE 1: mix GEMM  -> Fout fp32 = bf16(A)[o] + acc ; N=1024
//
// LDS 64 KiB: buf{0,1} x { A-half0 | A-half1 | B-half0 | B-half1 }, each
// half-region = [128 rows][32 bf16] = 8192 B, XOR-swizzled at 16B granularity.
#define PH_MFMA(M0)                                                            \
  __builtin_amdgcn_s_setprio(1);                                               \
  _Pragma("unroll")                                                            \
  for (int nf = 0; nf < 4; ++nf)                                               \
    acc[M0][nf] = __builtin_amdgcn_mfma_f32_16x16x32_bf16(                     \
        fa[M0], fb[nf], acc[M0][nf], 0, 0, 0);                                 \
  _Pragma("unroll")                                                            \
  for (int nf = 0; nf < 4; ++nf)                                               \
    acc[M0 + 1][nf] = __builtin_amdgcn_mfma_f32_16x16x32_bf16(                 \
        fa[M0 + 1], fb[nf], acc[M0 + 1][nf], 0, 0, 0);                         \
  __builtin_amdgcn_s_setprio(0);

#define MFMA_ALL()                                                             \
  __builtin_amdgcn_s_setprio(1);                                               \
  _Pragma("unroll")                                                            \
  for (int mf = 0; mf < 8; ++mf)                                               \
    _Pragma("unroll")                                                          \
    for (int nf = 0; nf < 4; ++nf)                                             \
      acc[mf][nf] = __builtin_amdgcn_mfma_f32_16x16x32_bf16(                   \
          fa[mf], fb[nf], acc[mf][nf], 0, 0, 0);                               \
  __builtin_amdgcn_s_setprio(0);

template <int MODE>
__global__ __launch_bounds__(512, 2) void gemm8(const bf16* __restrict__ Ab,
                                                const bf16* __restrict__ Bw,
                                                bf16* __restrict__ Vout,
                                                bf16* __restrict__ Rout,
                                                float* __restrict__ Fout) {
  __shared__ char lds[65536];
  constexpr int NTN = (MODE == 0) ? 8 : 4;

  // bijective XCD-chunk swizzle (nwg % 8 == 0)
  const int nwg = gridDim.x;
  const int id = blockIdx.x;
  const int wg = (id & 7) * (nwg >> 3) + (id >> 3);
  const int mt = wg / NTN, nt = wg % NTN;
  const int m0 = mt * 256, n0 = nt * 256;

  const int t = threadIdx.x;
  const int l = t & 63, w = t >> 6;          // 8 waves
  const int wm = w >> 2, wn = w & 3;         // 2 (M) x 4 (N) wave grid

  // ---- staging geometry: LDS dest is linear (wave base + lane*16); the global
  // source is pre-swizzled with the same involution the ds_read side applies.
  // dst_off = w*1024 + l*16 ; row = dst>>6 ; swz mask = ((row>>1)&3)<<4
  const int srow = w * 16 + (l >> 2);                       // 0..127
  const int scol = ((l & 3) ^ ((l >> 3) & 3)) << 4;         // 0..48, 16B-mult
  const char* Abase = (const char*)Ab;
  const char* Bbase = (const char*)Bw;
  const char* gA0 = Abase + (size_t)(m0 + srow) * 2048 + scol;
  const char* gA1 = gA0 + (size_t)128 * 2048;
  const char* gB0 = Bbase + (size_t)(n0 + srow) * 2048 + scol;
  const char* gB1 = gB0 + (size_t)128 * 2048;

  const int wb = w * 1024;                   // wave's staging slice in region

  // ---- read-side swizzled lane offset within a region
  const int ll = l & 15;
  const int laneoff = ((ll * 64) + ((l >> 4) << 4)) ^ (((ll >> 1) & 3) << 4);

  floatx4 acc[8][4];
  #pragma unroll
  for (int i = 0; i < 8; ++i)
    #pragma unroll
    for (int j = 0; j < 4; ++j) acc[i][j] = (floatx4){0.f, 0.f, 0.f, 0.f};

  // ---- prologue: stage B0(0),B1(0),A0(0),A1(0),B0(1),B1(1),A0(1)
  async_copy16(gB0, lds + 16384 + wb);            // B0(0) -> buf0
  async_copy16(gB1, lds + 24576 + wb);            // B1(0)
  async_copy16(gA0, lds + 0 + wb);                // A0(0)
  async_copy16(gA1, lds + 8192 + wb);             // A1(0)
  async_copy16(gB0 + 64, lds + 32768 + 16384 + wb); // B0(1) -> buf1
  async_copy16(gB1 + 64, lds + 32768 + 24576 + wb); // B1(1)
  async_copy16(gA0 + 64, lds + 32768 + 0 + wb);     // A0(1)
  gB0 += 128; gB1 += 128; gA0 += 128; gA1 += 64;
  VMCNT3();        // tile 0 landed; B0,B1,A0(1) still in flight
  S_BARRIER();

  short8 fa[8], fb[4];

  // ---- main loop: K = 1024, BK = 32 -> 32 K-tiles; blocks 0..29 full schedule
  for (int T = 0; T < 30; ++T) {
    const int cb = (T & 1) << 15;
    const char* smA = lds + cb + wm * 8192 + laneoff;
    const char* smB = lds + cb + 16384 + wn * 4096 + laneoff;
    // phase 0: read B(all) + A mf0-3 ; stage A1(T+1) -> other buffer
    #pragma unroll
    for (int nf = 0; nf < 4; ++nf) fb[nf] = *(const short8*)(smB + nf * 1024);
    #pragma unroll
    for (int mf = 0; mf < 4; ++mf) fa[mf] = *(const short8*)(smA + mf * 1024);
    async_copy16(gA1, lds + (cb ^ 32768) + 8192 + wb); gA1 += 64;
    S_BARRIER();
    PH_MFMA(0)
    S_BARRIER();
    // phase 1: read A mf4-7 ; stage B0(T+2) into this buffer (B0 consumed ph0)
    #pragma unroll
    for (int mf = 4; mf < 8; ++mf) fa[mf] = *(const short8*)(smA + mf * 1024);
    async_copy16(gB0, lds + cb + 16384 + wb); gB0 += 64;
    S_BARRIER();
    PH_MFMA(2)
    S_BARRIER();
    // phase 2: stage B1(T+2) (consumed ph0)
    async_copy16(gB1, lds + cb + 24576 + wb); gB1 += 64;
    S_BARRIER();
    PH_MFMA(4)
    S_BARRIER();
    // phase 3: stage A0(T+2) (consumed by ph1)
    async_copy16(gA0, lds + cb + wb); gA0 += 64;
    S_BARRIER();
    PH_MFMA(6)
    VMCNT3();      // tile T+1 landed; trio(T+2) stays in flight
    S_BARRIER();
  }

  // ---- block 30 (buf0): only stage A1(31); no same-buffer stages -> no bars
  {
    const char* smA = lds + wm * 8192 + laneoff;
    const char* smB = lds + 16384 + wn * 4096 + laneoff;
    #pragma unroll
    for (int nf = 0; nf < 4; ++nf) fb[nf] = *(const short8*)(smB + nf * 1024);
    #pragma unroll
    for (int mf = 0; mf < 8; ++mf) fa[mf] = *(const short8*)(smA + mf * 1024);
    async_copy16(gA1, lds + 32768 + 8192 + wb);   // A1(31) -> buf1
    MFMA_ALL()
    VMCNT0();
    S_BARRIER();
  }
  // ---- block 31 (buf1): no staging
  {
    const char* smA = lds + 32768 + wm * 8192 + laneoff;
    const char* smB = lds + 32768 + 16384 + wn * 4096 + laneoff;
    #pragma unroll
    for (int nf = 0; nf < 4; ++nf) fb[nf] = *(const short8*)(smB + nf * 1024);
    #pragma unroll
    for (int mf = 0; mf < 8; ++mf) fa[mf] = *(const short8*)(smA + mf * 1024);
    MFMA_ALL()
  }

  // ---- epilogue: C/D layout col = lane&15, row = (lane>>4)*4 + reg
  const int orow0 = m0 + wm * 128 + (l >> 4) * 4;
  const int ocol = n0 + wn * 64 + ll;
  if constexpr (MODE == 0) {
    const bool isr = (n0 >= 1024);
    bf16* outp = isr ? Rout : Vout;
    const int oc = isr ? (ocol - 1024) : ocol;
    #pragma unroll
    for (int mf = 0; mf < 8; ++mf) {
      #pragma unroll
      for (int i = 0; i < 4; ++i) {
        const size_t ro = (size_t)(orow0 + mf * 16 + i) * 1024 + oc;
        #pragma unroll
        for (int nf = 0; nf < 4; ++nf) {
          float cv = acc[mf][nf][i];
          if (isr) cv = 1.0f / (1.0f + __expf(-cv));
          outp[ro + nf * 16] = __float2bfloat16(cv);
        }
      }
    }
  } else {
    #pragma unroll
    for (int mf = 0; mf < 8; ++mf) {
      #pragma unroll
      for (int i = 0; i < 4; ++i) {
        const size_t ro = (size_t)(orow0 + mf * 16 + i) * 1024 + ocol;
        #pragma unroll
        for (int nf = 0; nf < 4; ++nf) {
          const size_t o = ro + nf * 16;
          Fout[o] = __bfloat162float(Ab[o]) + acc[mf][nf][i];
        }
      }
    }
  }
}

// ---------------- kernel 4: chunk-local decayed sums ----------------
__global__ void scan_partial(const bf16* __restrict__ V, float* __restrict__ sl) {
  const int idx = blockIdx.x * 256 + threadIdx.x;   // 131072 = B*NCHUNK*(D/2)
  const int d2 = idx & 511;
  const int c = (idx >> 9) & 15;
  const int b = idx >> 13;
  const bf162* V2 = (const bf162*)V;
  const size_t base = (size_t)(b * 2048 + c * 128) * 512 + d2;
  float s0 = 0.f, s1 = 0.f;
  for (int w = 0; w < CHUNKL; ++w) {
    const bf162 v = V2[base + (size_t)w * 512];
    s0 = DECAY_F * s0 + OM_F * __bfloat162float(v.x);
    s1 = DECAY_F * s1 + OM_F * __bfloat162float(v.y);
  }
  const int o = (b * 16 + c) * 1024 + d2 * 2;
  sl[o] = s0;
  sl[o + 1] = s1;
}

// ---------------- kernel 5: chunk-level scan ----------------
__global__ void scan_chunk(const float* __restrict__ state,
                           const float* __restrict__ sl,
                           float* __restrict__ sin_,
                           float* __restrict__ state_out,
                           float decayL) {
  const int idx = blockIdx.x * 256 + threadIdx.x;   // 16384 = B*D
  const int d = idx & 1023;
  const int b = idx >> 10;
  float s = state[idx];
  #pragma unroll
  for (int c = 0; c < NCHUNK; ++c) {
    const int o = (b * 16 + c) * 1024 + d;
    sin_[o] = s;
    s = decayL * s + sl[o];
  }
  state_out[idx] = s;
}

// ---------------- kernel 6: y_tmp = xb + r*s (in place over V) ----------
__global__ void scan_apply(const bf16* __restrict__ Xb,
                           const bf16* __restrict__ R,
                           const float* __restrict__ sin_,
                           bf16* __restrict__ VY) {
  const int idx = blockIdx.x * 256 + threadIdx.x;   // 131072
  const int d2 = idx & 511;
  const int c = (idx >> 9) & 15;
  const int b = idx >> 13;
  const bf162* R2 = (const bf162*)R;
  const bf162* X2 = (const bf162*)Xb;
  bf162* VY2 = (bf162*)VY;
  const size_t base = (size_t)(b * 2048 + c * 128) * 512 + d2;
  const int so = (b * 16 + c) * 1024 + d2 * 2;
  float s0 = sin_[so], s1 = sin_[so + 1];
  for (int w = 0; w < CHUNKL; ++w) {
    const size_t off = base + (size_t)w * 512;
    const bf162 v = VY2[off];
    const bf162 r = R2[off];
    const bf162 xx = X2[off];
    s0 = DECAY_F * s0 + OM_F * __bfloat162float(v.x);
    s1 = DECAY_F * s1 + OM_F * __bfloat162float(v.y);
    const float y0 = __bfloat162float(xx.x) + __bfloat162float(r.x) * s0;
    const float y1 = __bfloat162float(xx.y) + __bfloat162float(r.y) * s1;
    bf162 o;
    o.x = __float2bfloat16(y0);
    o.y = __float2bfloat16(y1);
    VY2[off] = o;
  }
}

extern "C" void kernel_launch(void* const* d_in, const int* in_sizes, int n_in,
                              void* d_out, int out_size, void* d_ws, size_t ws_size,
                              hipStream_t stream) {
  const float* x     = (const float*)d_in[0];
  const float* state = (const float*)d_in[1];
  const float* Wv    = (const float*)d_in[2];
  const float* Wr    = (const float*)d_in[3];
  const float* Wc    = (const float*)d_in[4];

  float* y_out = (float*)d_out;
  float* state_out = y_out + (size_t)MROWS * 1024;

  char* ws = (char*)d_ws;
  bf16* WT   = (bf16*)ws;                                    // 6 MiB
  bf16* Xb   = (bf16*)(ws + ((size_t)6 << 20));              // 64 MiB
  bf16* Vbuf = (bf16*)(ws + ((size_t)70 << 20));             // 64 MiB (also y_tmp)
  bf16* Rbuf = (bf16*)(ws + ((size_t)134 << 20));            // 64 MiB
  float* sl  = (float*)(ws + ((size_t)198 << 20));           // 1 MiB
  float* sin_ = (float*)(ws + ((size_t)199 << 20));          // 1 MiB
  bf16* WcT = WT + (size_t)2048 * 1024;

  const float decayL = (float)pow(0.99, (double)CHUNKL);

  prep_x<<<32768, 256, 0, stream>>>(x, Xb);
  prep_weights<<<dim3(32, 96), dim3(32, 8), 0, stream>>>(Wv, Wr, Wc, WT);
  gemm8<0><<<1024, 512, 0, stream>>>(Xb, WT, Vbuf, Rbuf, nullptr);
  scan_partial<<<512, 256, 0, stream>>>(Vbuf, sl);
  scan_chunk<<<64, 256, 0, stream>>>(state, sl, sin_, state_out, decayL);
  scan_apply<<<512, 256, 0, stream>>>(Xb, Rbuf, sin_, Vbuf);
  gemm8<1><<<512, 512, 0, stream>>>(Vbuf, WcT, nullptr, nullptr, y_out);
}

// Round 3
// 507.027 us; speedup vs baseline: 1.0432x; 1.0164x over previous
//
#include <hip/hip_runtime.h>
#include <hip/hip_bf16.h>
#include <math.h>

// LineRWKVBlock: y = (x + sigmoid(x@Wr) * scan(x@Wv)) ; y += y@Wc
// B=16, W=2048, D=1024, decay=0.99.
//
// R5: R4 post-mortem showed acc[8][4] lives in AGPRs -> ~256 regs/wave -> 1
// block/CU (occupancy 19.6%), so R4's 8 barriers/K-tile were fully exposed
// (MfmaUtil 35%). R5 keeps the 256^2/BK=32/8-wave geometry + swizzle (bank
// conflicts measured 0) but cuts sync to 2 barriers/K-tile:
//   ph0: stage A0,A1(T+1)->other buf ; read ALL 12 frags ; 16 MFMA (mf0-3)
//   bar  (cur-B consumed by all waves)
//   ph1: stage B0,B1(T+2)->cur-B ; 16 MFMA (mf4-7) ; vmcnt(2) ; bar
// vmcnt ledger: at T's vmcnt(2) in-flight = {A(T+1)x2, B(T+2)x2} -> drains
// exactly tile T+1, keeps B(T+2) flying. Counted waits never 0 in main loop.
//
// ws: WT 6 MiB | Xb 64 | V/y_tmp 64 | R 64 | sl 1 | s_in 1  = 200 MiB

#define MROWS 32768           // B*W
#define NCHUNK 16
#define CHUNKL 128
#define DECAY_F 0.99f
#define OM_F 0.01f

typedef __attribute__((ext_vector_type(8))) short short8;   // 8 bf16 (4 VGPRs)
typedef __attribute__((ext_vector_type(4))) float floatx4;

using bf16 = __hip_bfloat16;
using bf162 = __hip_bfloat162;

// async global->LDS, 16B per lane; lds base wave-uniform, HW scatters lane i at
// base + i*16.
__device__ __forceinline__ void async_copy16(const void* g, void* l) {
  __builtin_amdgcn_global_load_lds(
      (const __attribute__((address_space(1))) unsigned int*)g,
      (__attribute__((address_space(3))) unsigned int*)l, 16, 0, 0);
}

#define S_BARRIER() asm volatile("s_barrier" ::: "memory")
#define VMCNT2()                                                               \
  do {                                                                         \
    asm volatile("s_waitcnt vmcnt(2)" ::: "memory");                           \
    __builtin_amdgcn_sched_barrier(0);                                         \
  } while (0)
#define VMCNT0()                                                               \
  do {                                                                         \
    asm volatile("s_waitcnt vmcnt(0)" ::: "memory");                           \
    __builtin_amdgcn_sched_barrier(0);                                         \
  } while (0)

// ---------------- kernel 1: x fp32 -> bf16 ----------------
__global__ void prep_x(const float* __restrict__ X, bf16* __restrict__ Xb) {
  const int idx = blockIdx.x * 256 + threadIdx.x;   // 8388608 float4-groups
  const float4 v = ((const float4*)X)[idx];
  union { ushort4 u; bf16 h[4]; } pk;
  pk.h[0] = __float2bfloat16(v.x);
  pk.h[1] = __float2bfloat16(v.y);
  pk.h[2] = __float2bfloat16(v.z);
  pk.h[3] = __float2bfloat16(v.w);
  ((ushort4*)Xb)[idx] = pk.u;
}

// ---------------- kernel 2: weight transpose + bf16 cast ----------------
// WT rows 0..1023 = Wv^T, 1024..2047 = Wr^T, 2048..3071 = Wc^T ; WT[n][k]
__global__ void prep_weights(const float* __restrict__ Wv,
                             const float* __restrict__ Wr,
                             const float* __restrict__ Wc,
                             bf16* __restrict__ WT) {
  __shared__ float tile[32][33];
  const int bk = blockIdx.x * 32;   // k block
  const int bn = blockIdx.y * 32;   // global n block (0..3071)
  const float* src;
  int nbase = bn;
  if (bn < 1024)      { src = Wv; }
  else if (bn < 2048) { src = Wr; nbase = bn - 1024; }
  else                { src = Wc; nbase = bn - 2048; }
  const int tx = threadIdx.x;       // 32
  const int ty = threadIdx.y;       // 8
  #pragma unroll
  for (int i = ty; i < 32; i += 8)
    tile[i][tx] = src[(size_t)(bk + i) * 1024 + nbase + tx];  // tile[k][n]
  __syncthreads();
  #pragma unroll
  for (int i = ty; i < 32; i += 8)
    WT[(size_t)(bn + i) * 1024 + bk + tx] = __float2bfloat16(tile[tx][i]);
}

// ---------------- kernels 3/7: 256^2 BK=32 2-barrier pipelined GEMM --------
// MODE 0: v/r GEMM  -> Vout bf16 (nt<4), Rout = sigmoid (nt>=4); N=2048
// MODE 1: mix GEMM  -> Fout fp32 = bf16(A)[o] + acc ; N=1024
//
// LDS 64 KiB: buf{0,1} x { A0 | A1 | B0 | B1 }, each region = [128][32] bf16 =
// 8192 B, XOR-swizzled (byte ^= ((row>>1)&3)<<4) at 16B granularity.
#define PH_MFMA4(M0)                                                           \
  __builtin_amdgcn_s_setprio(1);                                               \
  _Pragma("unroll")                                                            \
  for (int mf = M0; mf < M0 + 4; ++mf)                                         \
    _Pragma("unroll")                                                          \
    for (int nf = 0; nf < 4; ++nf)                                             \
      acc[mf][nf] = __builtin_amdgcn_mfma_f32_16x16x32_bf16(                   \
          fa[mf], fb[nf], acc[mf][nf], 0, 0, 0);                               \
  __builtin_amdgcn_s_setprio(0);

#define MFMA_ALL()                                                             \
  __builtin_amdgcn_s_setprio(1);                                               \
  _Pragma("unroll")                                                            \
  for (int mf = 0; mf < 8; ++mf)                                               \
    _Pragma("unroll")                                                          \
    for (int nf = 0; nf < 4; ++nf)                                             \
      acc[mf][nf] = __builtin_amdgcn_mfma_f32_16x16x32_bf16(                   \
          fa[mf], fb[nf], acc[mf][nf], 0, 0, 0);                               \
  __builtin_amdgcn_s_setprio(0);

template <int MODE>
__global__ __launch_bounds__(512, 2) void gemm8(const bf16* __restrict__ Ab,
                                                const bf16* __restrict__ Bw,
                                                bf16* __restrict__ Vout,
                                                bf16* __restrict__ Rout,
                                                float* __restrict__ Fout) {
  __shared__ char lds[65536];
  constexpr int NTN = (MODE == 0) ? 8 : 4;

  // bijective XCD-chunk swizzle (nwg % 8 == 0)
  const int nwg = gridDim.x;
  const int id = blockIdx.x;
  const int wg = (id & 7) * (nwg >> 3) + (id >> 3);
  const int mt = wg / NTN, nt = wg % NTN;
  const int m0 = mt * 256, n0 = nt * 256;

  const int t = threadIdx.x;
  const int l = t & 63, w = t >> 6;          // 8 waves
  const int wm = w >> 2, wn = w & 3;         // 2 (M) x 4 (N) wave grid

  // ---- staging geometry: LDS dest linear (wave base + lane*16); global source
  // pre-swizzled with the same involution the ds_read side applies.
  // dst_off = w*1024 + l*16 ; row = dst>>6 ; swz mask = ((row>>1)&3)<<4
  const int srow = w * 16 + (l >> 2);                       // 0..127
  const int scol = ((l & 3) ^ ((l >> 3) & 3)) << 4;         // 0..48, 16B-mult
  const char* Abase = (const char*)Ab;
  const char* Bbase = (const char*)Bw;
  const char* gA0 = Abase + (size_t)(m0 + srow) * 2048 + scol;
  const char* gA1 = gA0 + (size_t)128 * 2048;
  const char* gB0 = Bbase + (size_t)(n0 + srow) * 2048 + scol;
  const char* gB1 = gB0 + (size_t)128 * 2048;

  const int wb = w * 1024;                   // wave's staging slice in region

  // ---- read-side swizzled lane offset within a region
  const int ll = l & 15;
  const int laneoff = ((ll * 64) + ((l >> 4) << 4)) ^ (((ll >> 1) & 3) << 4);

  floatx4 acc[8][4];
  #pragma unroll
  for (int i = 0; i < 8; ++i)
    #pragma unroll
    for (int j = 0; j < 4; ++j) acc[i][j] = (floatx4){0.f, 0.f, 0.f, 0.f};

  // ---- prologue: tile0 (A0,A1,B0,B1) + B0,B1(1); keep B(1) in flight
  async_copy16(gA0, lds + 0 + wb);                  // A0(0) buf0
  async_copy16(gA1, lds + 8192 + wb);               // A1(0)
  async_copy16(gB0, lds + 16384 + wb);              // B0(0)
  async_copy16(gB1, lds + 24576 + wb);              // B1(0)
  async_copy16(gB0 + 64, lds + 32768 + 16384 + wb); // B0(1) buf1
  async_copy16(gB1 + 64, lds + 32768 + 24576 + wb); // B1(1)
  gA0 += 64; gA1 += 64; gB0 += 128; gB1 += 128;
  VMCNT2();        // tile 0 landed; B(1) still in flight
  S_BARRIER();

  short8 fa[8], fb[4];

  // ---- main loop: K = 1024, BK = 32 -> 32 K-tiles; tiles 0..29 full schedule
  for (int T = 0; T < 30; ++T) {
    const int cb = (T & 1) << 15;
    const char* smA = lds + cb + wm * 8192 + laneoff;
    const char* smB = lds + cb + 16384 + wn * 4096 + laneoff;
    // ph0: stage A0,A1(T+1) -> other buffer (disjoint from cur reads);
    //      read ALL 12 fragments; cluster mf0-3 (fa4-7 drain under it)
    async_copy16(gA0, lds + (cb ^ 32768) + 0 + wb); gA0 += 64;
    async_copy16(gA1, lds + (cb ^ 32768) + 8192 + wb); gA1 += 64;
    #pragma unroll
    for (int nf = 0; nf < 4; ++nf) fb[nf] = *(const short8*)(smB + nf * 1024);
    #pragma unroll
    for (int mf = 0; mf < 8; ++mf) fa[mf] = *(const short8*)(smA + mf * 1024);
    PH_MFMA4(0)
    S_BARRIER();   // all waves' fb reads done (pre-MFMA lgkm) -> cur B free
    // ph1: stage B0,B1(T+2) -> cur B (consumed ph0, >=1 barrier ago)
    async_copy16(gB0, lds + cb + 16384 + wb); gB0 += 64;
    async_copy16(gB1, lds + cb + 24576 + wb); gB1 += 64;
    PH_MFMA4(4)
    VMCNT2();      // drain tile T+1 {A(T+1),B(T+1)}; keep B(T+2) in flight
    S_BARRIER();
  }

  // ---- tile 30 (buf0): stage only A(31) -> buf1; drain all; 1 barrier
  {
    const char* smA = lds + wm * 8192 + laneoff;
    const char* smB = lds + 16384 + wn * 4096 + laneoff;
    #pragma unroll
    for (int nf = 0; nf < 4; ++nf) fb[nf] = *(const short8*)(smB + nf * 1024);
    #pragma unroll
    for (int mf = 0; mf < 8; ++mf) fa[mf] = *(const short8*)(smA + mf * 1024);
    async_copy16(gA0, lds + 32768 + 0 + wb);      // A0(31)
    async_copy16(gA1, lds + 32768 + 8192 + wb);   // A1(31)
    MFMA_ALL()
    VMCNT0();
    S_BARRIER();
  }
  // ---- tile 31 (buf1): no staging, no barriers
  {
    const char* smA = lds + 32768 + wm * 8192 + laneoff;
    const char* smB = lds + 32768 + 16384 + wn * 4096 + laneoff;
    #pragma unroll
    for (int nf = 0; nf < 4; ++nf) fb[nf] = *(const short8*)(smB + nf * 1024);
    #pragma unroll
    for (int mf = 0; mf < 8; ++mf) fa[mf] = *(const short8*)(smA + mf * 1024);
    MFMA_ALL()
  }

  // ---- epilogue: C/D layout col = lane&15, row = (lane>>4)*4 + reg
  const int orow0 = m0 + wm * 128 + (l >> 4) * 4;
  const int ocol = n0 + wn * 64 + ll;
  if constexpr (MODE == 0) {
    const bool isr = (n0 >= 1024);
    bf16* outp = isr ? Rout : Vout;
    const int oc = isr ? (ocol - 1024) : ocol;
    #pragma unroll
    for (int mf = 0; mf < 8; ++mf) {
      #pragma unroll
      for (int i = 0; i < 4; ++i) {
        const size_t ro = (size_t)(orow0 + mf * 16 + i) * 1024 + oc;
        #pragma unroll
        for (int nf = 0; nf < 4; ++nf) {
          float cv = acc[mf][nf][i];
          if (isr) cv = 1.0f / (1.0f + __expf(-cv));
          outp[ro + nf * 16] = __float2bfloat16(cv);
        }
      }
    }
  } else {
    #pragma unroll
    for (int mf = 0; mf < 8; ++mf) {
      #pragma unroll
      for (int i = 0; i < 4; ++i) {
        const size_t ro = (size_t)(orow0 + mf * 16 + i) * 1024 + ocol;
        #pragma unroll
        for (int nf = 0; nf < 4; ++nf) {
          const size_t o = ro + nf * 16;
          Fout[o] = __bfloat162float(Ab[o]) + acc[mf][nf][i];
        }
      }
    }
  }
}

// ---------------- kernel 4: chunk-local decayed sums ----------------
__global__ void scan_partial(const bf16* __restrict__ V, float* __restrict__ sl) {
  const int idx = blockIdx.x * 256 + threadIdx.x;   // 131072 = B*NCHUNK*(D/2)
  const int d2 = idx & 511;
  const int c = (idx >> 9) & 15;
  const int b = idx >> 13;
  const bf162* V2 = (const bf162*)V;
  const size_t base = (size_t)(b * 2048 + c * 128) * 512 + d2;
  float s0 = 0.f, s1 = 0.f;
  for (int w = 0; w < CHUNKL; ++w) {
    const bf162 v = V2[base + (size_t)w * 512];
    s0 = DECAY_F * s0 + OM_F * __bfloat162float(v.x);
    s1 = DECAY_F * s1 + OM_F * __bfloat162float(v.y);
  }
  const int o = (b * 16 + c) * 1024 + d2 * 2;
  sl[o] = s0;
  sl[o + 1] = s1;
}

// ---------------- kernel 5: chunk-level scan ----------------
__global__ void scan_chunk(const float* __restrict__ state,
                           const float* __restrict__ sl,
                           float* __restrict__ sin_,
                           float* __restrict__ state_out,
                           float decayL) {
  const int idx = blockIdx.x * 256 + threadIdx.x;   // 16384 = B*D
  const int d = idx & 1023;
  const int b = idx >> 10;
  float s = state[idx];
  #pragma unroll
  for (int c = 0; c < NCHUNK; ++c) {
    const int o = (b * 16 + c) * 1024 + d;
    sin_[o] = s;
    s = decayL * s + sl[o];
  }
  state_out[idx] = s;
}

// ---------------- kernel 6: y_tmp = xb + r*s (in place over V) ----------
__global__ void scan_apply(const bf16* __restrict__ Xb,
                           const bf16* __restrict__ R,
                           const float* __restrict__ sin_,
                           bf16* __restrict__ VY) {
  const int idx = blockIdx.x * 256 + threadIdx.x;   // 131072
  const int d2 = idx & 511;
  const int c = (idx >> 9) & 15;
  const int b = idx >> 13;
  const bf162* R2 = (const bf162*)R;
  const bf162* X2 = (const bf162*)Xb;
  bf162* VY2 = (bf162*)VY;
  const size_t base = (size_t)(b * 2048 + c * 128) * 512 + d2;
  const int so = (b * 16 + c) * 1024 + d2 * 2;
  float s0 = sin_[so], s1 = sin_[so + 1];
  for (int w = 0; w < CHUNKL; ++w) {
    const size_t off = base + (size_t)w * 512;
    const bf162 v = VY2[off];
    const bf162 r = R2[off];
    const bf162 xx = X2[off];
    s0 = DECAY_F * s0 + OM_F * __bfloat162float(v.x);
    s1 = DECAY_F * s1 + OM_F * __bfloat162float(v.y);
    const float y0 = __bfloat162float(xx.x) + __bfloat162float(r.x) * s0;
    const float y1 = __bfloat162float(xx.y) + __bfloat162float(r.y) * s1;
    bf162 o;
    o.x = __float2bfloat16(y0);
    o.y = __float2bfloat16(y1);
    VY2[off] = o;
  }
}

extern "C" void kernel_launch(void* const* d_in, const int* in_sizes, int n_in,
                              void* d_out, int out_size, void* d_ws, size_t ws_size,
                              hipStream_t stream) {
  const float* x     = (const float*)d_in[0];
  const float* state = (const float*)d_in[1];
  const float* Wv    = (const float*)d_in[2];
  const float* Wr    = (const float*)d_in[3];
  const float* Wc    = (const float*)d_in[4];

  float* y_out = (float*)d_out;
  float* state_out = y_out + (size_t)MROWS * 1024;

  char* ws = (char*)d_ws;
  bf16* WT   = (bf16*)ws;                                    // 6 MiB
  bf16* Xb   = (bf16*)(ws + ((size_t)6 << 20));              // 64 MiB
  bf16* Vbuf = (bf16*)(ws + ((size_t)70 << 20));             // 64 MiB (also y_tmp)
  bf16* Rbuf = (bf16*)(ws + ((size_t)134 << 20));            // 64 MiB
  float* sl  = (float*)(ws + ((size_t)198 << 20));           // 1 MiB
  float* sin_ = (float*)(ws + ((size_t)199 << 20));          // 1 MiB
  bf16* WcT = WT + (size_t)2048 * 1024;

  const float decayL = (float)pow(0.99, (double)CHUNKL);

  prep_x<<<32768, 256, 0, stream>>>(x, Xb);
  prep_weights<<<dim3(32, 96), dim3(32, 8), 0, stream>>>(Wv, Wr, Wc, WT);
  gemm8<0><<<1024, 512, 0, stream>>>(Xb, WT, Vbuf, Rbuf, nullptr);
  scan_partial<<<512, 256, 0, stream>>>(Vbuf, sl);
  scan_chunk<<<64, 256, 0, stream>>>(state, sl, sin_, state_out, decayL);
  scan_apply<<<512, 256, 0, stream>>>(Xb, Rbuf, sin_, Vbuf);
  gemm8<1><<<512, 512, 0, stream>>>(Vbuf, WcT, nullptr, nullptr, y_out);
}